// Round 2
// baseline (611.239 us; speedup 1.0000x reference)
//
#include <hip/hip_runtime.h>
#include <math.h>

#define EPB  32    // edges per block
#define FSTR 264   // f LDS row stride (shorts): 256 + 8 pad
#define MSTR 136   // m LDS row stride (shorts): 128 + 8 pad

typedef __attribute__((ext_vector_type(8))) short short8;
typedef __attribute__((ext_vector_type(4))) float f32x4;

__device__ __forceinline__ unsigned short f2bf(float x) {
    unsigned int u = __float_as_uint(x);
    u += 0x7fffu + ((u >> 16) & 1u);   // round-to-nearest-even
    return (unsigned short)(u >> 16);
}
__device__ __forceinline__ float fsilu(float x) {
    return x * (1.0f / (1.0f + __expf(-x)));
}
__device__ __forceinline__ float fsigm(float x) {
    return 1.0f / (1.0f + __expf(-x));
}
__device__ __forceinline__ void atomAddF(float* p, float v) {
    unsafeAtomicAdd(p, v);   // hardware global_atomic_add_f32
}

// ---------------------------------------------------------------------------
// Weight prep: transpose fp32 [K][128] -> bf16 [128][K] row-major.
// ---------------------------------------------------------------------------
struct PrepArgs { const float* src[10]; };

__global__ __launch_bounds__(256) void prep_weights(PrepArgs pa, short* __restrict__ wsb) {
    int idx = blockIdx.x * 256 + threadIdx.x;      // 0..245759, grid = 960
    int pair = idx / 49152;
    int rem  = idx - pair * 49152;
    int second = (rem >= 32768) ? 1 : 0;
    int mi = pair * 2 + second;
    int within = second ? (rem - 32768) : rem;
    int n, k, K;
    if (second) { K = 128; n = within >> 7; k = within & 127; }
    else        { K = 256; n = within >> 8; k = within & 255; }
    int dstoff = pair * 49152 + second * 32768;
    wsb[dstoff + n * K + k] = (short)f2bf(pa.src[mi][k * 128 + n]);
}

// ---------------------------------------------------------------------------
// Counting sort of edges by dst: hist -> exclusive scan -> scatter
// ---------------------------------------------------------------------------
__global__ __launch_bounds__(256) void hist_kernel(const int* __restrict__ dst, int E,
                                                   int* __restrict__ hist) {
    int i = blockIdx.x * 256 + threadIdx.x;
    if (i < E) atomicAdd(&hist[dst[i]], 1);
}

__global__ __launch_bounds__(1024) void scan_kernel(const int* __restrict__ hist,
                                                    int* __restrict__ cursor) {
    // 10000 bins, 1024 threads, 10 bins/thread (threads 0..999 active)
    __shared__ int s[1024];
    const int t = threadIdx.x;
    const int base = t * 10;
    int sum = 0;
    if (t < 1000)
        for (int i = 0; i < 10; i++) sum += hist[base + i];
    s[t] = sum;
    __syncthreads();
    for (int off = 1; off < 1024; off <<= 1) {
        int v = (t >= off) ? s[t - off] : 0;
        __syncthreads();
        s[t] += v;
        __syncthreads();
    }
    if (t < 1000) {
        int run = (t == 0) ? 0 : s[t - 1];
        for (int i = 0; i < 10; i++) { cursor[base + i] = run; run += hist[base + i]; }
    }
}

__global__ __launch_bounds__(256) void scatter_kernel(const int* __restrict__ src,
                                                      const int* __restrict__ dst, int E,
                                                      int* __restrict__ cursor,
                                                      int* __restrict__ ssrc,
                                                      int* __restrict__ sdst) {
    int i = blockIdx.x * 256 + threadIdx.x;
    if (i < E) {
        int d = dst[i];
        int p = atomicAdd(&cursor[d], 1);
        ssrc[p] = src[i];
        sdst[p] = d;
    }
}

// ---------------------------------------------------------------------------
// Edge kernel: 32 edges/block, 256 threads (4 waves), wave w owns cols [32w,32w+32)
// mfma_f32_16x16x32_bf16: A[m=lane&15][k=quad*8+j], B[k=quad*8+j][n=lane&15],
// C/D[row=quad*4+r][col=lane&15]
// Epilogue: dst-sorted edges -> in-LDS column scan, one atomic per dst segment.
// ---------------------------------------------------------------------------
__global__ __launch_bounds__(256, 4) void edge_kernel(
    const float* __restrict__ hsrc_tab, const float* __restrict__ hdst_tab,
    const float* __restrict__ xsrc_tab, const float* __restrict__ xdst_tab,
    const int* __restrict__ esrc, const int* __restrict__ edst,
    const short* __restrict__ W1t, const float* __restrict__ b1v, const float* __restrict__ w256,
    const short* __restrict__ W2t, const float* __restrict__ b2v,
    const float* __restrict__ aW, const float* __restrict__ abv,
    const short* __restrict__ cW1t, const float* __restrict__ cb1v, const float* __restrict__ cw256,
    const short* __restrict__ cW2t, const float* __restrict__ cb2v, const float* __restrict__ cW3,
    float* __restrict__ hne, float* __restrict__ xne)
{
    __shared__ __align__(16) char  regionA[EPB * FSTR * 2]; // f bf16 [32][264] | msg f32 [32][132]
    __shared__ __align__(16) short mh_lds[EPB * MSTR];
    __shared__ __align__(16) short mc_lds[EPB * MSTR];
    __shared__ float dij_l[EPB];
    __shared__ float sg_l[EPB];       // gate (h phase) then sv (x phase)
    __shared__ float xdf[3][EPB];
    __shared__ int   dstl[EPB];
    __shared__ float gp[4][EPB];

    short* f_lds = (short*)regionA;
    float* msg   = (float*)regionA;   // stride 132 floats

    const int t  = threadIdx.x;
    const int eb = blockIdx.x * EPB;

    // ---- gather h_src/h_dst -> bf16 LDS (8 threads per edge, 16 cols each) ----
    {
        const int e = t >> 3, q = t & 7;
        const int eid = eb + e;
        const int s = esrc[eid], d = edst[eid];
        if (q == 0) dstl[e] = d;
        const float4* hs = (const float4*)(hsrc_tab + (size_t)s * 128 + q * 16);
        const float4* hd = (const float4*)(hdst_tab + (size_t)d * 128 + q * 16);
        short* frow = &f_lds[e * FSTR + q * 16];
#pragma unroll
        for (int i = 0; i < 4; i++) {
            float4 v = hs[i];
            *(ushort4*)(frow + i * 4) =
                make_ushort4(f2bf(v.x), f2bf(v.y), f2bf(v.z), f2bf(v.w));
        }
#pragma unroll
        for (int i = 0; i < 4; i++) {
            float4 v = hd[i];
            *(ushort4*)(frow + 128 + i * 4) =
                make_ushort4(f2bf(v.x), f2bf(v.y), f2bf(v.z), f2bf(v.w));
        }
    }
    if (t < EPB) {
        const int eid = eb + t;
        const int s = esrc[eid], d = edst[eid];
        float dx = xsrc_tab[s * 3 + 0] - xdst_tab[d * 3 + 0];
        float dy = xsrc_tab[s * 3 + 1] - xdst_tab[d * 3 + 1];
        float dz = xsrc_tab[s * 3 + 2] - xdst_tab[d * 3 + 2];
        float dd = sqrtf(dx * dx + dy * dy + dz * dz);
        float inv = 1.0f / (dd + 1.0f);
        dij_l[t] = dd;
        xdf[0][t] = dx * inv; xdf[1][t] = dy * inv; xdf[2][t] = dz * inv;
    }
    __syncthreads();

    const int ln = t & 63, wv = t >> 6;
    const int lrow = ln & 15, quad = ln >> 4;
    const int c0 = wv * 32 + lrow, c1 = c0 + 16;

    // ---- GEMM1e: m_h = silu(f @ eW1 + b1 + dij*eW1[256]) ----
    {
        short8 bf0[8], bf1[8];
#pragma unroll
        for (int kt = 0; kt < 8; kt++) {
            bf0[kt] = *(const short8*)(W1t + c0 * 256 + kt * 32 + quad * 8);
            bf1[kt] = *(const short8*)(W1t + c1 * 256 + kt * 32 + quad * 8);
        }
        const float w0 = w256[c0], w1 = w256[c1];
        const float bb0 = b1v[c0], bb1 = b1v[c1];
#pragma unroll
        for (int mt = 0; mt < 2; mt++) {
            short8 af[8];
#pragma unroll
            for (int kt = 0; kt < 8; kt++)
                af[kt] = *(const short8*)(&f_lds[(mt * 16 + lrow) * FSTR + kt * 32 + quad * 8]);
            f32x4 a0 = {0.f, 0.f, 0.f, 0.f}, a1 = {0.f, 0.f, 0.f, 0.f};
#pragma unroll
            for (int kt = 0; kt < 8; kt++) {
                a0 = __builtin_amdgcn_mfma_f32_16x16x32_bf16(af[kt], bf0[kt], a0, 0, 0, 0);
                a1 = __builtin_amdgcn_mfma_f32_16x16x32_bf16(af[kt], bf1[kt], a1, 0, 0, 0);
            }
#pragma unroll
            for (int r = 0; r < 4; r++) {
                const int erow = mt * 16 + quad * 4 + r;
                const float dv = dij_l[erow];
                mh_lds[erow * MSTR + c0] = (short)f2bf(fsilu(a0[r] + bb0 + dv * w0));
                mh_lds[erow * MSTR + c1] = (short)f2bf(fsilu(a1[r] + bb1 + dv * w1));
            }
        }
    }
    // ---- GEMM1c: m_c = silu(f @ cW1 + cb1 + dij*cW1[256]) ----
    {
        short8 bf0[8], bf1[8];
#pragma unroll
        for (int kt = 0; kt < 8; kt++) {
            bf0[kt] = *(const short8*)(cW1t + c0 * 256 + kt * 32 + quad * 8);
            bf1[kt] = *(const short8*)(cW1t + c1 * 256 + kt * 32 + quad * 8);
        }
        const float w0 = cw256[c0], w1 = cw256[c1];
        const float bb0 = cb1v[c0], bb1 = cb1v[c1];
#pragma unroll
        for (int mt = 0; mt < 2; mt++) {
            short8 af[8];
#pragma unroll
            for (int kt = 0; kt < 8; kt++)
                af[kt] = *(const short8*)(&f_lds[(mt * 16 + lrow) * FSTR + kt * 32 + quad * 8]);
            f32x4 a0 = {0.f, 0.f, 0.f, 0.f}, a1 = {0.f, 0.f, 0.f, 0.f};
#pragma unroll
            for (int kt = 0; kt < 8; kt++) {
                a0 = __builtin_amdgcn_mfma_f32_16x16x32_bf16(af[kt], bf0[kt], a0, 0, 0, 0);
                a1 = __builtin_amdgcn_mfma_f32_16x16x32_bf16(af[kt], bf1[kt], a1, 0, 0, 0);
            }
#pragma unroll
            for (int r = 0; r < 4; r++) {
                const int erow = mt * 16 + quad * 4 + r;
                const float dv = dij_l[erow];
                mc_lds[erow * MSTR + c0] = (short)f2bf(fsilu(a0[r] + bb0 + dv * w0));
                mc_lds[erow * MSTR + c1] = (short)f2bf(fsilu(a1[r] + bb1 + dv * w1));
            }
        }
    }
    __syncthreads();   // f dead from here on

    // ---- GEMM2e: m2 = silu(m_h @ eW2 + b2); gate partials via butterfly ----
    float m2s[2][8];
    {
        short8 bf0[4], bf1[4];
#pragma unroll
        for (int kt = 0; kt < 4; kt++) {
            bf0[kt] = *(const short8*)(W2t + c0 * 128 + kt * 32 + quad * 8);
            bf1[kt] = *(const short8*)(W2t + c1 * 128 + kt * 32 + quad * 8);
        }
        const float aw0 = aW[c0], aw1 = aW[c1];
        const float bb0 = b2v[c0], bb1 = b2v[c1];
#pragma unroll
        for (int mt = 0; mt < 2; mt++) {
            short8 af[4];
#pragma unroll
            for (int kt = 0; kt < 4; kt++)
                af[kt] = *(const short8*)(&mh_lds[(mt * 16 + lrow) * MSTR + kt * 32 + quad * 8]);
            f32x4 a0 = {0.f, 0.f, 0.f, 0.f}, a1 = {0.f, 0.f, 0.f, 0.f};
#pragma unroll
            for (int kt = 0; kt < 4; kt++) {
                a0 = __builtin_amdgcn_mfma_f32_16x16x32_bf16(af[kt], bf0[kt], a0, 0, 0, 0);
                a1 = __builtin_amdgcn_mfma_f32_16x16x32_bf16(af[kt], bf1[kt], a1, 0, 0, 0);
            }
#pragma unroll
            for (int r = 0; r < 4; r++) {
                float v0 = fsilu(a0[r] + bb0);
                float v1 = fsilu(a1[r] + bb1);
                m2s[mt][r] = v0; m2s[mt][4 + r] = v1;
                float g = v0 * aw0 + v1 * aw1;
                g += __shfl_xor(g, 1, 64);
                g += __shfl_xor(g, 2, 64);
                g += __shfl_xor(g, 4, 64);
                g += __shfl_xor(g, 8, 64);
                if (lrow == 0) gp[wv][mt * 16 + quad * 4 + r] = g;
            }
        }
    }
    __syncthreads();
    if (t < EPB) sg_l[t] = fsigm(gp[0][t] + gp[1][t] + gp[2][t] + gp[3][t] + abv[0]);
    __syncthreads();

    // gated messages -> msg LDS (overlays dead f region)
#pragma unroll
    for (int mt = 0; mt < 2; mt++)
#pragma unroll
        for (int r = 0; r < 4; r++) {
            const int erow = mt * 16 + quad * 4 + r;
            const float gv = sg_l[erow];
            msg[erow * 132 + c0] = m2s[mt][r] * gv;
            msg[erow * 132 + c1] = m2s[mt][4 + r] * gv;
        }
    __syncthreads();

    // ---- h segmented column reduction: one atomic per dst segment per col ----
    if (t < 128) {
        const int col = t;
        float acc = 0.0f;
        int cur = dstl[0];
#pragma unroll 4
        for (int e = 0; e < EPB; e++) {
            const int d = dstl[e];
            if (d != cur) {
                atomAddF(&hne[(size_t)cur * 128 + col], acc);
                acc = 0.0f; cur = d;
            }
            acc += msg[e * 132 + col];
        }
        atomAddF(&hne[(size_t)cur * 128 + col], acc);
    }

    // ---- GEMM2c: c2 = silu(m_c @ cW2 + cb2); sv = c2 @ cW3 ----
    {
        short8 bf0[4], bf1[4];
#pragma unroll
        for (int kt = 0; kt < 4; kt++) {
            bf0[kt] = *(const short8*)(cW2t + c0 * 128 + kt * 32 + quad * 8);
            bf1[kt] = *(const short8*)(cW2t + c1 * 128 + kt * 32 + quad * 8);
        }
        const float cw0 = cW3[c0], cw1 = cW3[c1];
        const float bb0 = cb2v[c0], bb1 = cb2v[c1];
#pragma unroll
        for (int mt = 0; mt < 2; mt++) {
            short8 af[4];
#pragma unroll
            for (int kt = 0; kt < 4; kt++)
                af[kt] = *(const short8*)(&mc_lds[(mt * 16 + lrow) * MSTR + kt * 32 + quad * 8]);
            f32x4 a0 = {0.f, 0.f, 0.f, 0.f}, a1 = {0.f, 0.f, 0.f, 0.f};
#pragma unroll
            for (int kt = 0; kt < 4; kt++) {
                a0 = __builtin_amdgcn_mfma_f32_16x16x32_bf16(af[kt], bf0[kt], a0, 0, 0, 0);
                a1 = __builtin_amdgcn_mfma_f32_16x16x32_bf16(af[kt], bf1[kt], a1, 0, 0, 0);
            }
#pragma unroll
            for (int r = 0; r < 4; r++) {
                float v0 = fsilu(a0[r] + bb0);
                float v1 = fsilu(a1[r] + bb1);
                float g = v0 * cw0 + v1 * cw1;
                g += __shfl_xor(g, 1, 64);
                g += __shfl_xor(g, 2, 64);
                g += __shfl_xor(g, 4, 64);
                g += __shfl_xor(g, 8, 64);
                if (lrow == 0) gp[wv][mt * 16 + quad * 4 + r] = g;
            }
        }
    }
    __syncthreads();
    if (t < EPB) sg_l[t] = gp[0][t] + gp[1][t] + gp[2][t] + gp[3][t];
    __syncthreads();

    // ---- x segmented reduction: 3 cols ----
    if (t < 3) {
        float acc = 0.0f;
        int cur = dstl[0];
        for (int e = 0; e < EPB; e++) {
            const int d = dstl[e];
            if (d != cur) {
                atomAddF(&xne[cur * 3 + t], acc);
                acc = 0.0f; cur = d;
            }
            acc += sg_l[e] * xdf[t][e];
        }
        atomAddF(&xne[cur * 3 + t], acc);
    }
}

// ---------------------------------------------------------------------------
// Node kernel: reads accumulators in d_out, overwrites with final outputs.
// ---------------------------------------------------------------------------
__global__ __launch_bounds__(256) void node_kernel(
    const float* __restrict__ h_lig, const float* __restrict__ zlig,
    const short* __restrict__ W1t, const float* __restrict__ b1v,
    const short* __restrict__ W2t, const float* __restrict__ b2v,
    const float* __restrict__ x_lig,
    float* __restrict__ acc_h, float* __restrict__ acc_x)
{
    __shared__ __align__(16) short f_lds[64 * FSTR];
    __shared__ __align__(16) short m_lds[64 * MSTR];
    const int t = threadIdx.x;
    const int nb = blockIdx.x * 64;

    {
        const int e = t >> 2, q = t & 3;
        const int node = nb + e;
        short* frow = &f_lds[e * FSTR + q * 32];
        if (node < 10000) {
            const float zi = 1.0f / zlig[node];
            const float4* hp = (const float4*)(h_lig + (size_t)node * 128 + q * 32);
            const float4* np = (const float4*)(acc_h + (size_t)node * 128 + q * 32);
#pragma unroll
            for (int i = 0; i < 8; i++) {
                float4 v = hp[i];
                *(ushort4*)(frow + i * 4) =
                    make_ushort4(f2bf(v.x), f2bf(v.y), f2bf(v.z), f2bf(v.w));
            }
#pragma unroll
            for (int i = 0; i < 8; i++) {
                float4 v = np[i];
                *(ushort4*)(frow + 128 + i * 4) =
                    make_ushort4(f2bf(v.x * zi), f2bf(v.y * zi), f2bf(v.z * zi), f2bf(v.w * zi));
            }
        } else {
            const ushort4 zz = make_ushort4(0, 0, 0, 0);
#pragma unroll
            for (int i = 0; i < 8; i++) {
                *(ushort4*)(frow + i * 4) = zz;
                *(ushort4*)(frow + 128 + i * 4) = zz;
            }
        }
    }
    __syncthreads();

    const int ln = t & 63, wv = t >> 6;
    const int lrow = ln & 15, quad = ln >> 4;
    const int c0 = wv * 32 + lrow, c1 = c0 + 16;

    {
        short8 bf0[8], bf1[8];
#pragma unroll
        for (int kt = 0; kt < 8; kt++) {
            bf0[kt] = *(const short8*)(W1t + c0 * 256 + kt * 32 + quad * 8);
            bf1[kt] = *(const short8*)(W1t + c1 * 256 + kt * 32 + quad * 8);
        }
        const float bb0 = b1v[c0], bb1 = b1v[c1];
#pragma unroll
        for (int mt = 0; mt < 4; mt++) {
            short8 af[8];
#pragma unroll
            for (int kt = 0; kt < 8; kt++)
                af[kt] = *(const short8*)(&f_lds[(mt * 16 + lrow) * FSTR + kt * 32 + quad * 8]);
            f32x4 a0 = {0.f, 0.f, 0.f, 0.f}, a1 = {0.f, 0.f, 0.f, 0.f};
#pragma unroll
            for (int kt = 0; kt < 8; kt++) {
                a0 = __builtin_amdgcn_mfma_f32_16x16x32_bf16(af[kt], bf0[kt], a0, 0, 0, 0);
                a1 = __builtin_amdgcn_mfma_f32_16x16x32_bf16(af[kt], bf1[kt], a1, 0, 0, 0);
            }
#pragma unroll
            for (int r = 0; r < 4; r++) {
                const int erow = mt * 16 + quad * 4 + r;
                m_lds[erow * MSTR + c0] = (short)f2bf(fsilu(a0[r] + bb0));
                m_lds[erow * MSTR + c1] = (short)f2bf(fsilu(a1[r] + bb1));
            }
        }
    }
    __syncthreads();

    {
        short8 bf0[4], bf1[4];
#pragma unroll
        for (int kt = 0; kt < 4; kt++) {
            bf0[kt] = *(const short8*)(W2t + c0 * 128 + kt * 32 + quad * 8);
            bf1[kt] = *(const short8*)(W2t + c1 * 128 + kt * 32 + quad * 8);
        }
        const float bb0 = b2v[c0], bb1 = b2v[c1];
#pragma unroll
        for (int mt = 0; mt < 4; mt++) {
            short8 af[4];
#pragma unroll
            for (int kt = 0; kt < 4; kt++)
                af[kt] = *(const short8*)(&m_lds[(mt * 16 + lrow) * MSTR + kt * 32 + quad * 8]);
            f32x4 a0 = {0.f, 0.f, 0.f, 0.f}, a1 = {0.f, 0.f, 0.f, 0.f};
#pragma unroll
            for (int kt = 0; kt < 4; kt++) {
                a0 = __builtin_amdgcn_mfma_f32_16x16x32_bf16(af[kt], bf0[kt], a0, 0, 0, 0);
                a1 = __builtin_amdgcn_mfma_f32_16x16x32_bf16(af[kt], bf1[kt], a1, 0, 0, 0);
            }
#pragma unroll
            for (int r = 0; r < 4; r++) {
                const int node = nb + mt * 16 + quad * 4 + r;
                if (node < 10000) {
                    acc_h[(size_t)node * 128 + c0] = a0[r] + bb0 + h_lig[(size_t)node * 128 + c0];
                    acc_h[(size_t)node * 128 + c1] = a1[r] + bb1 + h_lig[(size_t)node * 128 + c1];
                }
            }
        }
    }
    if (t < 64) {
        const int node = nb + t;
        if (node < 10000) {
            const float zi = 1.0f / zlig[node];
#pragma unroll
            for (int i = 0; i < 3; i++)
                acc_x[node * 3 + i] = x_lig[node * 3 + i] + acc_x[node * 3 + i] * zi;
        }
    }
}

extern "C" void kernel_launch(void* const* d_in, const int* in_sizes, int n_in,
                              void* d_out, int out_size, void* d_ws, size_t ws_size,
                              hipStream_t stream)
{
    (void)in_sizes; (void)n_in;
    const float* h_lig  = (const float*)d_in[0];
    const float* h_kp   = (const float*)d_in[1];
    const float* x_lig  = (const float*)d_in[2];
    const float* x_kp   = (const float*)d_in[3];
    const float* z_lig  = (const float*)d_in[4];
    const float* ll_eW1 = (const float*)d_in[5];
    const float* ll_eb1 = (const float*)d_in[6];
    const float* ll_eW2 = (const float*)d_in[7];
    const float* ll_eb2 = (const float*)d_in[8];
    const float* ll_aW  = (const float*)d_in[9];
    const float* ll_ab  = (const float*)d_in[10];
    const float* ll_cW1 = (const float*)d_in[11];
    const float* ll_cb1 = (const float*)d_in[12];
    const float* ll_cW2 = (const float*)d_in[13];
    const float* ll_cb2 = (const float*)d_in[14];
    const float* ll_cW3 = (const float*)d_in[15];
    const float* kl_eW1 = (const float*)d_in[16];
    const float* kl_eb1 = (const float*)d_in[17];
    const float* kl_eW2 = (const float*)d_in[18];
    const float* kl_eb2 = (const float*)d_in[19];
    const float* kl_aW  = (const float*)d_in[20];
    const float* kl_ab  = (const float*)d_in[21];
    const float* kl_cW1 = (const float*)d_in[22];
    const float* kl_cb1 = (const float*)d_in[23];
    const float* kl_cW2 = (const float*)d_in[24];
    const float* kl_cb2 = (const float*)d_in[25];
    const float* kl_cW3 = (const float*)d_in[26];
    const float* n_W1   = (const float*)d_in[27];
    const float* n_b1   = (const float*)d_in[28];
    const float* n_W2   = (const float*)d_in[29];
    const float* n_b2   = (const float*)d_in[30];
    const int* ll_src = (const int*)d_in[31];
    const int* ll_dst = (const int*)d_in[32];
    const int* kl_src = (const int*)d_in[33];
    const int* kl_dst = (const int*)d_in[34];

    float* out = (float*)d_out;
    float* hne = out;                 // [10000,128]
    float* xne = out + 1280000;       // [10000,3]

    // ws layout
    char* wsc = (char*)d_ws;
    short* wsb = (short*)wsc;                             // weights: 491520 B
    int* ll_ssrc = (int*)(wsc + 491520);                  // 1,280,000 B
    int* ll_sdst = (int*)(wsc + 1771520);                 // 1,280,000 B
    int* kl_ssrc = (int*)(wsc + 3051520);                 //   640,000 B
    int* kl_sdst = (int*)(wsc + 3691520);                 //   640,000 B
    int* hist_ll = (int*)(wsc + 4331520);                 //    40,000 B
    int* cur_ll  = (int*)(wsc + 4371520);                 //    40,000 B
    int* hist_kl = (int*)(wsc + 4411520);                 //    40,000 B
    int* cur_kl  = (int*)(wsc + 4451520);                 // end 4,491,520 B
    const bool can_sort = (ws_size >= 4491520);

    hipMemsetAsync(d_out, 0, (size_t)out_size * sizeof(float), stream);

    PrepArgs pa;
    pa.src[0] = ll_eW1; pa.src[1] = ll_eW2; pa.src[2] = ll_cW1; pa.src[3] = ll_cW2;
    pa.src[4] = kl_eW1; pa.src[5] = kl_eW2; pa.src[6] = kl_cW1; pa.src[7] = kl_cW2;
    pa.src[8] = n_W1;   pa.src[9] = n_W2;
    prep_weights<<<960, 256, 0, stream>>>(pa, wsb);

    const int* e_ll_src = ll_src; const int* e_ll_dst = ll_dst;
    const int* e_kl_src = kl_src; const int* e_kl_dst = kl_dst;
    if (can_sort) {
        hipMemsetAsync(hist_ll, 0, 160000, stream);  // zeroes hist_ll..cur_kl region start
        hist_kernel<<<1250, 256, 0, stream>>>(ll_dst, 320000, hist_ll);
        scan_kernel<<<1, 1024, 0, stream>>>(hist_ll, cur_ll);
        scatter_kernel<<<1250, 256, 0, stream>>>(ll_src, ll_dst, 320000, cur_ll, ll_ssrc, ll_sdst);
        hist_kernel<<<625, 256, 0, stream>>>(kl_dst, 160000, hist_kl);
        scan_kernel<<<1, 1024, 0, stream>>>(hist_kl, cur_kl);
        scatter_kernel<<<625, 256, 0, stream>>>(kl_src, kl_dst, 160000, cur_kl, kl_ssrc, kl_sdst);
        e_ll_src = ll_ssrc; e_ll_dst = ll_sdst;
        e_kl_src = kl_ssrc; e_kl_dst = kl_sdst;
    }

    // ws weight layout (shorts): pair p at p*49152, W1-like (32768) then W2-like (16384)
    edge_kernel<<<10000, 256, 0, stream>>>(
        h_lig, h_lig, x_lig, x_lig, e_ll_src, e_ll_dst,
        wsb + 0,      ll_eb1, ll_eW1 + 256 * 128,
        wsb + 32768,  ll_eb2, ll_aW, ll_ab,
        wsb + 49152,  ll_cb1, ll_cW1 + 256 * 128,
        wsb + 81920,  ll_cb2, ll_cW3,
        hne, xne);
    edge_kernel<<<5000, 256, 0, stream>>>(
        h_kp, h_lig, x_kp, x_lig, e_kl_src, e_kl_dst,
        wsb + 98304,  kl_eb1, kl_eW1 + 256 * 128,
        wsb + 131072, kl_eb2, kl_aW, kl_ab,
        wsb + 147456, kl_cb1, kl_cW1 + 256 * 128,
        wsb + 180224, kl_cb2, kl_cW3,
        hne, xne);

    node_kernel<<<157, 256, 0, stream>>>(
        h_lig, z_lig, wsb + 196608, n_b1, wsb + 229376, n_b2,
        x_lig, hne, xne);
}

// Round 3
// 446.931 us; speedup vs baseline: 1.3676x; 1.3676x over previous
//
#include <hip/hip_runtime.h>
#include <math.h>

#define EPB  64    // edges per block
#define MSTR 136   // m LDS row stride (shorts): 128 + 8 pad

typedef __attribute__((ext_vector_type(8))) short short8;
typedef __attribute__((ext_vector_type(4))) float f32x4;

__device__ __forceinline__ unsigned short f2bf(float x) {
    unsigned int u = __float_as_uint(x);
    u += 0x7fffu + ((u >> 16) & 1u);   // round-to-nearest-even
    return (unsigned short)(u >> 16);
}
__device__ __forceinline__ float bf2f(short v) {
    return __uint_as_float(((unsigned int)(unsigned short)v) << 16);
}
__device__ __forceinline__ float fsilu(float x) {
    return x * (1.0f / (1.0f + __expf(-x)));
}
__device__ __forceinline__ float fsigm(float x) {
    return 1.0f / (1.0f + __expf(-x));
}
__device__ __forceinline__ void atomAddF(float* p, float v) {
    unsafeAtomicAdd(p, v);   // hardware global_atomic_add_f32
}

// ---------------------------------------------------------------------------
// Setup: transpose 10 weight mats fp32 [K][128] -> bf16 [128][K], zero d_out,
// zero hist. One launch.
// ---------------------------------------------------------------------------
struct PrepArgs { const float* src[10]; };

__global__ __launch_bounds__(256) void setup_kernel(PrepArgs pa, short* __restrict__ wsb,
                                                    float* __restrict__ out, int out_n,
                                                    int* __restrict__ hist) {
    int idx = blockIdx.x * 256 + threadIdx.x;
    if (idx < 245760) {
        int pair = idx / 49152;
        int rem  = idx - pair * 49152;
        int second = (rem >= 32768) ? 1 : 0;
        int mi = pair * 2 + second;
        int within = second ? (rem - 32768) : rem;
        int n, k, K;
        if (second) { K = 128; n = within >> 7; k = within & 127; }
        else        { K = 256; n = within >> 8; k = within & 255; }
        int dstoff = pair * 49152 + second * 32768;
        wsb[dstoff + n * K + k] = (short)f2bf(pa.src[mi][k * 128 + n]);
        return;
    }
    idx -= 245760;
    if (idx < out_n) { out[idx] = 0.0f; return; }
    idx -= out_n;
    if (idx < 20000) hist[idx] = 0;
}

// ---------------------------------------------------------------------------
// Counting sort (both edge types in one launch each stage)
// ---------------------------------------------------------------------------
__global__ __launch_bounds__(256) void hist_kernel(const int* __restrict__ lld,
                                                   const int* __restrict__ kld,
                                                   int* __restrict__ hist) {
    int i = blockIdx.x * 256 + threadIdx.x;   // grid covers 480000
    if (i < 320000) atomicAdd(&hist[lld[i]], 1);
    else if (i < 480000) atomicAdd(&hist[10000 + kld[i - 320000]], 1);
}

__global__ __launch_bounds__(256) void scan_kernel(const int* __restrict__ hist,
                                                   int* __restrict__ cursor) {
    // blockIdx.x = edge type; 10000 bins each; 256 threads x 40 bins
    __shared__ int sbuf[256];
    const int b = blockIdx.x, t = threadIdx.x;
    const int* h = hist + b * 10000;
    int* cur = cursor + b * 10000;
    const int base = t * 40;
    int s = 0;
#pragma unroll 8
    for (int i = 0; i < 40; i++) if (base + i < 10000) s += h[base + i];
    sbuf[t] = s;
    __syncthreads();
    for (int off = 1; off < 256; off <<= 1) {
        int v = (t >= off) ? sbuf[t - off] : 0;
        __syncthreads();
        sbuf[t] += v;
        __syncthreads();
    }
    int run = sbuf[t] - s;   // exclusive prefix
    for (int i = 0; i < 40; i++) {
        if (base + i < 10000) { cur[base + i] = run; run += h[base + i]; }
    }
}

__global__ __launch_bounds__(256) void scatter_kernel(const int* __restrict__ lls,
                                                      const int* __restrict__ lld,
                                                      const int* __restrict__ kls,
                                                      const int* __restrict__ kld,
                                                      int* __restrict__ cursor,
                                                      int* __restrict__ ll_ssrc, int* __restrict__ ll_sdst,
                                                      int* __restrict__ kl_ssrc, int* __restrict__ kl_sdst) {
    int i = blockIdx.x * 256 + threadIdx.x;
    if (i < 320000) {
        int d = lld[i];
        int p = atomicAdd(&cursor[d], 1);
        ll_ssrc[p] = lls[i]; ll_sdst[p] = d;
    } else if (i < 480000) {
        int j = i - 320000;
        int d = kld[j];
        int p = atomicAdd(&cursor[10000 + d], 1);
        kl_ssrc[p] = kls[j]; kl_sdst[p] = d;
    }
}

// ---------------------------------------------------------------------------
// Projection kernel: P = A @ W1part (+bias for dst tables), bf16 out [rows][256]
// 8 tables via blockIdx.y. B-frags from W1t [n][256], kt base selects K-half.
// ---------------------------------------------------------------------------
struct ProjDesc { const float* A; const short* Bt; short* out; const float* bias;
                  int rows; int ktb; int co; int hasb; };
struct ProjArgs { ProjDesc d[8]; };

__global__ __launch_bounds__(256) void proj_kernel(ProjArgs pa) {
    const ProjDesc pd = pa.d[blockIdx.y];
    const int tile = blockIdx.x;
    if (tile * 64 >= pd.rows) return;
    __shared__ __align__(16) short a_lds[64 * MSTR];
    const int t = threadIdx.x;
    {
        const int r = t >> 2, q = t & 3;
        const int node = tile * 64 + r;
        short* arow = a_lds + r * MSTR + q * 32;
        if (node < pd.rows) {
            const float* ap = pd.A + (size_t)node * 128 + q * 32;
#pragma unroll
            for (int i = 0; i < 4; i++) {
                float4 v0 = *(const float4*)(ap + i * 8);
                float4 v1 = *(const float4*)(ap + i * 8 + 4);
                short8 o;
                o[0] = (short)f2bf(v0.x); o[1] = (short)f2bf(v0.y);
                o[2] = (short)f2bf(v0.z); o[3] = (short)f2bf(v0.w);
                o[4] = (short)f2bf(v1.x); o[5] = (short)f2bf(v1.y);
                o[6] = (short)f2bf(v1.z); o[7] = (short)f2bf(v1.w);
                *(short8*)(arow + i * 8) = o;
            }
        } else {
            short8 z = {0, 0, 0, 0, 0, 0, 0, 0};
#pragma unroll
            for (int i = 0; i < 4; i++) *(short8*)(arow + i * 8) = z;
        }
    }
    __syncthreads();

    const int ln = t & 63, wv = t >> 6;
    const int lrow = ln & 15, quad = ln >> 4;
    const int c0 = wv * 32 + lrow, c1 = c0 + 16;

    short8 bf0[4], bf1[4];
#pragma unroll
    for (int kt = 0; kt < 4; kt++) {
        bf0[kt] = *(const short8*)(pd.Bt + c0 * 256 + (pd.ktb + kt) * 32 + quad * 8);
        bf1[kt] = *(const short8*)(pd.Bt + c1 * 256 + (pd.ktb + kt) * 32 + quad * 8);
    }
    const float bb0 = pd.hasb ? pd.bias[c0] : 0.0f;
    const float bb1 = pd.hasb ? pd.bias[c1] : 0.0f;
#pragma unroll
    for (int mt = 0; mt < 4; mt++) {
        short8 af[4];
#pragma unroll
        for (int kt = 0; kt < 4; kt++)
            af[kt] = *(const short8*)(&a_lds[(mt * 16 + lrow) * MSTR + kt * 32 + quad * 8]);
        f32x4 a0 = {0.f, 0.f, 0.f, 0.f}, a1 = {0.f, 0.f, 0.f, 0.f};
#pragma unroll
        for (int kt = 0; kt < 4; kt++) {
            a0 = __builtin_amdgcn_mfma_f32_16x16x32_bf16(af[kt], bf0[kt], a0, 0, 0, 0);
            a1 = __builtin_amdgcn_mfma_f32_16x16x32_bf16(af[kt], bf1[kt], a1, 0, 0, 0);
        }
#pragma unroll
        for (int r = 0; r < 4; r++) {
            const int node = tile * 64 + mt * 16 + quad * 4 + r;
            if (node < pd.rows) {
                pd.out[(size_t)node * 256 + pd.co + c0] = (short)f2bf(a0[r] + bb0);
                pd.out[(size_t)node * 256 + pd.co + c1] = (short)f2bf(a1[r] + bb1);
            }
        }
    }
}

// ---------------------------------------------------------------------------
// Edge kernel: GEMM1 replaced by gather of per-node projections.
// 64 edges/block, 256 threads (4 waves), wave w owns cols [32w,32w+32).
// ll blocks [0,split), kl blocks [split,grid). dst-sorted -> segmented scan.
// ---------------------------------------------------------------------------
struct EdgeSet {
    const short *Ps, *Pd;        // [nodes][256] bf16: cols 0..127 e-proj, 128..255 c-proj (b1 folded in Pd)
    const float *xs, *xd;
    const int *esrc, *edst;      // dst-sorted
    const float *w256e, *w256c;  // dij coefficient rows (fp32, from原 W1 row 256)
    const short *W2t, *cW2t;     // [128][128] bf16
    const float *b2e, *b2c;
    const float *aW, *ab, *cW3;
};
struct EdgePair { EdgeSet s[2]; int split; };

__global__ __launch_bounds__(256, 4) void edge_kernel(EdgePair ep,
                                                      float* __restrict__ hne,
                                                      float* __restrict__ xne)
{
    __shared__ __align__(16) char mbuf[34816];  // mh(17408)+mc(17408) | msg f32 (33792)
    __shared__ float sv_l[EPB];
    __shared__ float gate_l[EPB];
    __shared__ float xdf[3][EPB];
    __shared__ int   dstl[EPB];
    __shared__ float gp[4][EPB];

    short* mh = (short*)mbuf;
    short* mc = (short*)(mbuf + 17408);
    float* msg = (float*)mbuf;          // stride 132 floats, overlays mh+mc after GEMMs

    const int isKL = (blockIdx.x >= ep.split) ? 1 : 0;
    const EdgeSet P = ep.s[isKL];
    const int bid = blockIdx.x - (isKL ? ep.split : 0);
    const int eb = bid * EPB;
    const int t = threadIdx.x;

    // ---- phase 0: gather projections, fuse add+dij*w+silu, pack bf16 to LDS ----
    {
        const int e = t >> 2, q = t & 3;
        const int eid = eb + e;
        const int s = P.esrc[eid], d = P.edst[eid];
        float dx = P.xs[s * 3 + 0] - P.xd[d * 3 + 0];
        float dy = P.xs[s * 3 + 1] - P.xd[d * 3 + 1];
        float dz = P.xs[s * 3 + 2] - P.xd[d * 3 + 2];
        float dd = sqrtf(dx * dx + dy * dy + dz * dz);
        if (q == 0) {
            dstl[e] = d;
            float inv = 1.0f / (dd + 1.0f);
            xdf[0][e] = dx * inv; xdf[1][e] = dy * inv; xdf[2][e] = dz * inv;
        }
        const short* psrow = P.Ps + (size_t)s * 256 + q * 32;
        const short* pdrow = P.Pd + (size_t)d * 256 + q * 32;
#pragma unroll
        for (int path = 0; path < 2; path++) {
            const short* ps = psrow + path * 128;
            const short* pq = pdrow + path * 128;
            const float* wq = (path ? P.w256c : P.w256e) + q * 32;
            short* mrow = (path ? mc : mh) + e * MSTR + q * 32;
#pragma unroll
            for (int i = 0; i < 4; i++) {
                short8 a = *(const short8*)(ps + i * 8);
                short8 b = *(const short8*)(pq + i * 8);
                float4 wA = *(const float4*)(wq + i * 8);
                float4 wB = *(const float4*)(wq + i * 8 + 4);
                short8 o;
                o[0] = (short)f2bf(fsilu(bf2f(a[0]) + bf2f(b[0]) + dd * wA.x));
                o[1] = (short)f2bf(fsilu(bf2f(a[1]) + bf2f(b[1]) + dd * wA.y));
                o[2] = (short)f2bf(fsilu(bf2f(a[2]) + bf2f(b[2]) + dd * wA.z));
                o[3] = (short)f2bf(fsilu(bf2f(a[3]) + bf2f(b[3]) + dd * wA.w));
                o[4] = (short)f2bf(fsilu(bf2f(a[4]) + bf2f(b[4]) + dd * wB.x));
                o[5] = (short)f2bf(fsilu(bf2f(a[5]) + bf2f(b[5]) + dd * wB.y));
                o[6] = (short)f2bf(fsilu(bf2f(a[6]) + bf2f(b[6]) + dd * wB.z));
                o[7] = (short)f2bf(fsilu(bf2f(a[7]) + bf2f(b[7]) + dd * wB.w));
                *(short8*)(mrow + i * 8) = o;
            }
        }
    }
    __syncthreads();   // B1

    const int ln = t & 63, wv = t >> 6;
    const int lrow = ln & 15, quad = ln >> 4;
    const int c0 = wv * 32 + lrow, c1 = c0 + 16;

    // ---- GEMM2c: c2 = silu(m_c @ cW2 + cb2); sv = c2 @ cW3 ----
    {
        short8 bf0[4], bf1[4];
#pragma unroll
        for (int kt = 0; kt < 4; kt++) {
            bf0[kt] = *(const short8*)(P.cW2t + c0 * 128 + kt * 32 + quad * 8);
            bf1[kt] = *(const short8*)(P.cW2t + c1 * 128 + kt * 32 + quad * 8);
        }
        const float cw0 = P.cW3[c0], cw1 = P.cW3[c1];
        const float bb0 = P.b2c[c0], bb1 = P.b2c[c1];
#pragma unroll
        for (int mt = 0; mt < 4; mt++) {
            short8 af[4];
#pragma unroll
            for (int kt = 0; kt < 4; kt++)
                af[kt] = *(const short8*)(&mc[(mt * 16 + lrow) * MSTR + kt * 32 + quad * 8]);
            f32x4 a0 = {0.f, 0.f, 0.f, 0.f}, a1 = {0.f, 0.f, 0.f, 0.f};
#pragma unroll
            for (int kt = 0; kt < 4; kt++) {
                a0 = __builtin_amdgcn_mfma_f32_16x16x32_bf16(af[kt], bf0[kt], a0, 0, 0, 0);
                a1 = __builtin_amdgcn_mfma_f32_16x16x32_bf16(af[kt], bf1[kt], a1, 0, 0, 0);
            }
#pragma unroll
            for (int r = 0; r < 4; r++) {
                float v0 = fsilu(a0[r] + bb0);
                float v1 = fsilu(a1[r] + bb1);
                float g = v0 * cw0 + v1 * cw1;
                g += __shfl_xor(g, 1, 64);
                g += __shfl_xor(g, 2, 64);
                g += __shfl_xor(g, 4, 64);
                g += __shfl_xor(g, 8, 64);
                if (lrow == 0) gp[wv][mt * 16 + quad * 4 + r] = g;
            }
        }
    }
    __syncthreads();   // B2
    if (t < EPB) sv_l[t] = gp[0][t] + gp[1][t] + gp[2][t] + gp[3][t];
    __syncthreads();   // B3 (gp reused below)

    // ---- GEMM2e: m2 = silu(m_h @ eW2 + b2); gate partials ----
    float m2s[4][8];
    {
        short8 bf0[4], bf1[4];
#pragma unroll
        for (int kt = 0; kt < 4; kt++) {
            bf0[kt] = *(const short8*)(P.W2t + c0 * 128 + kt * 32 + quad * 8);
            bf1[kt] = *(const short8*)(P.W2t + c1 * 128 + kt * 32 + quad * 8);
        }
        const float aw0 = P.aW[c0], aw1 = P.aW[c1];
        const float bb0 = P.b2e[c0], bb1 = P.b2e[c1];
#pragma unroll
        for (int mt = 0; mt < 4; mt++) {
            short8 af[4];
#pragma unroll
            for (int kt = 0; kt < 4; kt++)
                af[kt] = *(const short8*)(&mh[(mt * 16 + lrow) * MSTR + kt * 32 + quad * 8]);
            f32x4 a0 = {0.f, 0.f, 0.f, 0.f}, a1 = {0.f, 0.f, 0.f, 0.f};
#pragma unroll
            for (int kt = 0; kt < 4; kt++) {
                a0 = __builtin_amdgcn_mfma_f32_16x16x32_bf16(af[kt], bf0[kt], a0, 0, 0, 0);
                a1 = __builtin_amdgcn_mfma_f32_16x16x32_bf16(af[kt], bf1[kt], a1, 0, 0, 0);
            }
#pragma unroll
            for (int r = 0; r < 4; r++) {
                float v0 = fsilu(a0[r] + bb0);
                float v1 = fsilu(a1[r] + bb1);
                m2s[mt][r] = v0; m2s[mt][4 + r] = v1;
                float g = v0 * aw0 + v1 * aw1;
                g += __shfl_xor(g, 1, 64);
                g += __shfl_xor(g, 2, 64);
                g += __shfl_xor(g, 4, 64);
                g += __shfl_xor(g, 8, 64);
                if (lrow == 0) gp[wv][mt * 16 + quad * 4 + r] = g;
            }
        }
    }
    __syncthreads();   // B4
    if (t < EPB) gate_l[t] = fsigm(gp[0][t] + gp[1][t] + gp[2][t] + gp[3][t] + P.ab[0]);
    __syncthreads();   // B5 (mh/mc dead -> msg overlay)

#pragma unroll
    for (int mt = 0; mt < 4; mt++)
#pragma unroll
        for (int r = 0; r < 4; r++) {
            const int erow = mt * 16 + quad * 4 + r;
            const float gv = gate_l[erow];
            msg[erow * 132 + c0] = m2s[mt][r] * gv;
            msg[erow * 132 + c1] = m2s[mt][4 + r] * gv;
        }
    __syncthreads();   // B6

    // ---- segmented reductions (dst-sorted): h cols by t<128, x by t in [128,131) ----
    if (t < 128) {
        const int col = t;
        float acc = 0.0f;
        int cur = dstl[0];
#pragma unroll 4
        for (int e = 0; e < EPB; e++) {
            const int d = dstl[e];
            if (d != cur) {
                atomAddF(&hne[(size_t)cur * 128 + col], acc);
                acc = 0.0f; cur = d;
            }
            acc += msg[e * 132 + col];
        }
        atomAddF(&hne[(size_t)cur * 128 + col], acc);
    } else if (t < 131) {
        const int ax = t - 128;
        float acc = 0.0f;
        int cur = dstl[0];
        for (int e = 0; e < EPB; e++) {
            const int d = dstl[e];
            if (d != cur) {
                atomAddF(&xne[cur * 3 + ax], acc);
                acc = 0.0f; cur = d;
            }
            acc += sv_l[e] * xdf[ax][e];
        }
        atomAddF(&xne[cur * 3 + ax], acc);
    }
}

// ---------------------------------------------------------------------------
// Node kernel (unchanged structure from R2)
// ---------------------------------------------------------------------------
#define FSTR 264
__global__ __launch_bounds__(256) void node_kernel(
    const float* __restrict__ h_lig, const float* __restrict__ zlig,
    const short* __restrict__ W1t, const float* __restrict__ b1v,
    const short* __restrict__ W2t, const float* __restrict__ b2v,
    const float* __restrict__ x_lig,
    float* __restrict__ acc_h, float* __restrict__ acc_x)
{
    __shared__ __align__(16) short f_lds[64 * FSTR];
    __shared__ __align__(16) short m_lds[64 * MSTR];
    const int t = threadIdx.x;
    const int nb = blockIdx.x * 64;

    {
        const int e = t >> 2, q = t & 3;
        const int node = nb + e;
        short* frow = &f_lds[e * FSTR + q * 32];
        if (node < 10000) {
            const float zi = 1.0f / zlig[node];
            const float4* hp = (const float4*)(h_lig + (size_t)node * 128 + q * 32);
            const float4* np = (const float4*)(acc_h + (size_t)node * 128 + q * 32);
#pragma unroll
            for (int i = 0; i < 8; i++) {
                float4 v = hp[i];
                *(ushort4*)(frow + i * 4) =
                    make_ushort4(f2bf(v.x), f2bf(v.y), f2bf(v.z), f2bf(v.w));
            }
#pragma unroll
            for (int i = 0; i < 8; i++) {
                float4 v = np[i];
                *(ushort4*)(frow + 128 + i * 4) =
                    make_ushort4(f2bf(v.x * zi), f2bf(v.y * zi), f2bf(v.z * zi), f2bf(v.w * zi));
            }
        } else {
            const ushort4 zz = make_ushort4(0, 0, 0, 0);
#pragma unroll
            for (int i = 0; i < 8; i++) {
                *(ushort4*)(frow + i * 4) = zz;
                *(ushort4*)(frow + 128 + i * 4) = zz;
            }
        }
    }
    __syncthreads();

    const int ln = t & 63, wv = t >> 6;
    const int lrow = ln & 15, quad = ln >> 4;
    const int c0 = wv * 32 + lrow, c1 = c0 + 16;

    {
        short8 bf0[8], bf1[8];
#pragma unroll
        for (int kt = 0; kt < 8; kt++) {
            bf0[kt] = *(const short8*)(W1t + c0 * 256 + kt * 32 + quad * 8);
            bf1[kt] = *(const short8*)(W1t + c1 * 256 + kt * 32 + quad * 8);
        }
        const float bb0 = b1v[c0], bb1 = b1v[c1];
#pragma unroll
        for (int mt = 0; mt < 4; mt++) {
            short8 af[8];
#pragma unroll
            for (int kt = 0; kt < 8; kt++)
                af[kt] = *(const short8*)(&f_lds[(mt * 16 + lrow) * FSTR + kt * 32 + quad * 8]);
            f32x4 a0 = {0.f, 0.f, 0.f, 0.f}, a1 = {0.f, 0.f, 0.f, 0.f};
#pragma unroll
            for (int kt = 0; kt < 8; kt++) {
                a0 = __builtin_amdgcn_mfma_f32_16x16x32_bf16(af[kt], bf0[kt], a0, 0, 0, 0);
                a1 = __builtin_amdgcn_mfma_f32_16x16x32_bf16(af[kt], bf1[kt], a1, 0, 0, 0);
            }
#pragma unroll
            for (int r = 0; r < 4; r++) {
                const int erow = mt * 16 + quad * 4 + r;
                m_lds[erow * MSTR + c0] = (short)f2bf(fsilu(a0[r] + bb0));
                m_lds[erow * MSTR + c1] = (short)f2bf(fsilu(a1[r] + bb1));
            }
        }
    }
    __syncthreads();

    {
        short8 bf0[4], bf1[4];
#pragma unroll
        for (int kt = 0; kt < 4; kt++) {
            bf0[kt] = *(const short8*)(W2t + c0 * 128 + kt * 32 + quad * 8);
            bf1[kt] = *(const short8*)(W2t + c1 * 128 + kt * 32 + quad * 8);
        }
        const float bb0 = b2v[c0], bb1 = b2v[c1];
#pragma unroll
        for (int mt = 0; mt < 4; mt++) {
            short8 af[4];
#pragma unroll
            for (int kt = 0; kt < 4; kt++)
                af[kt] = *(const short8*)(&m_lds[(mt * 16 + lrow) * MSTR + kt * 32 + quad * 8]);
            f32x4 a0 = {0.f, 0.f, 0.f, 0.f}, a1 = {0.f, 0.f, 0.f, 0.f};
#pragma unroll
            for (int kt = 0; kt < 4; kt++) {
                a0 = __builtin_amdgcn_mfma_f32_16x16x32_bf16(af[kt], bf0[kt], a0, 0, 0, 0);
                a1 = __builtin_amdgcn_mfma_f32_16x16x32_bf16(af[kt], bf1[kt], a1, 0, 0, 0);
            }
#pragma unroll
            for (int r = 0; r < 4; r++) {
                const int node = nb + mt * 16 + quad * 4 + r;
                if (node < 10000) {
                    acc_h[(size_t)node * 128 + c0] = a0[r] + bb0 + h_lig[(size_t)node * 128 + c0];
                    acc_h[(size_t)node * 128 + c1] = a1[r] + bb1 + h_lig[(size_t)node * 128 + c1];
                }
            }
        }
    }
    if (t < 64) {
        const int node = nb + t;
        if (node < 10000) {
            const float zi = 1.0f / zlig[node];
#pragma unroll
            for (int i = 0; i < 3; i++)
                acc_x[node * 3 + i] = x_lig[node * 3 + i] + acc_x[node * 3 + i] * zi;
        }
    }
}

extern "C" void kernel_launch(void* const* d_in, const int* in_sizes, int n_in,
                              void* d_out, int out_size, void* d_ws, size_t ws_size,
                              hipStream_t stream)
{
    (void)in_sizes; (void)n_in; (void)ws_size;
    const float* h_lig  = (const float*)d_in[0];
    const float* h_kp   = (const float*)d_in[1];
    const float* x_lig  = (const float*)d_in[2];
    const float* x_kp   = (const float*)d_in[3];
    const float* z_lig  = (const float*)d_in[4];
    const float* ll_eW1 = (const float*)d_in[5];
    const float* ll_eb1 = (const float*)d_in[6];
    const float* ll_eW2 = (const float*)d_in[7];
    const float* ll_eb2 = (const float*)d_in[8];
    const float* ll_aW  = (const float*)d_in[9];
    const float* ll_ab  = (const float*)d_in[10];
    const float* ll_cW1 = (const float*)d_in[11];
    const float* ll_cb1 = (const float*)d_in[12];
    const float* ll_cW2 = (const float*)d_in[13];
    const float* ll_cb2 = (const float*)d_in[14];
    const float* ll_cW3 = (const float*)d_in[15];
    const float* kl_eW1 = (const float*)d_in[16];
    const float* kl_eb1 = (const float*)d_in[17];
    const float* kl_eW2 = (const float*)d_in[18];
    const float* kl_eb2 = (const float*)d_in[19];
    const float* kl_aW  = (const float*)d_in[20];
    const float* kl_ab  = (const float*)d_in[21];
    const float* kl_cW1 = (const float*)d_in[22];
    const float* kl_cb1 = (const float*)d_in[23];
    const float* kl_cW2 = (const float*)d_in[24];
    const float* kl_cb2 = (const float*)d_in[25];
    const float* kl_cW3 = (const float*)d_in[26];
    const float* n_W1   = (const float*)d_in[27];
    const float* n_b1   = (const float*)d_in[28];
    const float* n_W2   = (const float*)d_in[29];
    const float* n_b2   = (const float*)d_in[30];
    const int* ll_src = (const int*)d_in[31];
    const int* ll_dst = (const int*)d_in[32];
    const int* kl_src = (const int*)d_in[33];
    const int* kl_dst = (const int*)d_in[34];

    float* out = (float*)d_out;
    float* hne = out;                 // [10000,128]
    float* xne = out + 1280000;       // [10000,3]

    // ws layout (bytes) — ~20.9 MB total
    char* wsc = (char*)d_ws;
    short* wsb    = (short*)wsc;                 //       0: weights (491,520 B)
    short* P_ll_s = (short*)(wsc +   491520);    // 5,120,000 B  [10000][256]
    short* P_ll_d = (short*)(wsc +  5611520);    // 5,120,000 B
    short* P_kl_s = (short*)(wsc + 10731520);    // 1,024,000 B  [2000][256]
    short* P_kl_d = (short*)(wsc + 11755520);    // 5,120,000 B
    int* ll_ssrc  = (int*)(wsc + 16875520);      // 1,280,000 B
    int* ll_sdst  = (int*)(wsc + 18155520);      // 1,280,000 B
    int* kl_ssrc  = (int*)(wsc + 19435520);      //   640,000 B
    int* kl_sdst  = (int*)(wsc + 20075520);      //   640,000 B
    int* hist     = (int*)(wsc + 20715520);      //    80,000 B (20000 ints)
    int* cursor   = (int*)(wsc + 20795520);      //    80,000 B -> end 20,875,520

    // 1. setup: weight transpose + zero out + zero hist
    {
        int total = 245760 + out_size + 20000;
        PrepArgs pa;
        pa.src[0] = ll_eW1; pa.src[1] = ll_eW2; pa.src[2] = ll_cW1; pa.src[3] = ll_cW2;
        pa.src[4] = kl_eW1; pa.src[5] = kl_eW2; pa.src[6] = kl_cW1; pa.src[7] = kl_cW2;
        pa.src[8] = n_W1;   pa.src[9] = n_W2;
        setup_kernel<<<(total + 255) / 256, 256, 0, stream>>>(pa, wsb, out, out_size, hist);
    }
    // 2-4. counting sort by dst (both edge types)
    hist_kernel<<<1875, 256, 0, stream>>>(ll_dst, kl_dst, hist);
    scan_kernel<<<2, 256, 0, stream>>>(hist, cursor);
    scatter_kernel<<<1875, 256, 0, stream>>>(ll_src, ll_dst, kl_src, kl_dst, cursor,
                                             ll_ssrc, ll_sdst, kl_ssrc, kl_sdst);
    // 5. per-node projections (GEMM1 hoisted out of edges); b1 folded into dst tables
    {
        ProjArgs pj;
        pj.d[0] = { h_lig, wsb + 0,      P_ll_s, ll_eb1, 10000, 0, 0,   0 };
        pj.d[1] = { h_lig, wsb + 49152,  P_ll_s, ll_cb1, 10000, 0, 128, 0 };
        pj.d[2] = { h_lig, wsb + 0,      P_ll_d, ll_eb1, 10000, 4, 0,   1 };
        pj.d[3] = { h_lig, wsb + 49152,  P_ll_d, ll_cb1, 10000, 4, 128, 1 };
        pj.d[4] = { h_kp,  wsb + 98304,  P_kl_s, kl_eb1,  2000, 0, 0,   0 };
        pj.d[5] = { h_kp,  wsb + 147456, P_kl_s, kl_cb1,  2000, 0, 128, 0 };
        pj.d[6] = { h_lig, wsb + 98304,  P_kl_d, kl_eb1, 10000, 4, 0,   1 };
        pj.d[7] = { h_lig, wsb + 147456, P_kl_d, kl_cb1, 10000, 4, 128, 1 };
        proj_kernel<<<dim3(157, 8), 256, 0, stream>>>(pj);
    }
    // 6. edges (ll + kl in one launch)
    {
        EdgePair ep;
        ep.split = 5000;
        ep.s[0] = { P_ll_s, P_ll_d, x_lig, x_lig, ll_ssrc, ll_sdst,
                    ll_eW1 + 256 * 128, ll_cW1 + 256 * 128,
                    wsb + 32768, wsb + 81920, ll_eb2, ll_cb2,
                    ll_aW, ll_ab, ll_cW3 };
        ep.s[1] = { P_kl_s, P_kl_d, x_kp, x_lig, kl_ssrc, kl_sdst,
                    kl_eW1 + 256 * 128, kl_cW1 + 256 * 128,
                    wsb + 131072, wsb + 180224, kl_eb2, kl_cb2,
                    kl_aW, kl_ab, kl_cW3 };
        edge_kernel<<<7500, 256, 0, stream>>>(ep, hne, xne);
    }
    // 7. node MLP + final outputs
    node_kernel<<<157, 256, 0, stream>>>(
        h_lig, z_lig, wsb + 196608, n_b1, wsb + 229376, n_b2,
        x_lig, hne, xne);
}

// Round 4
// 412.465 us; speedup vs baseline: 1.4819x; 1.0836x over previous
//
#include <hip/hip_runtime.h>
#include <math.h>

#define EPB  32    // edges per block
#define MSTR 136   // m LDS row stride (shorts): 128 + 8 pad
#define FSTR 264   // node-kernel f stride

typedef __attribute__((ext_vector_type(8))) short short8;
typedef __attribute__((ext_vector_type(4))) float f32x4;

__device__ __forceinline__ unsigned short f2bf(float x) {
    unsigned int u = __float_as_uint(x);
    u += 0x7fffu + ((u >> 16) & 1u);   // round-to-nearest-even
    return (unsigned short)(u >> 16);
}
__device__ __forceinline__ float bf2f(short v) {
    return __uint_as_float(((unsigned int)(unsigned short)v) << 16);
}
__device__ __forceinline__ float fsilu(float x) {
    return x * (1.0f / (1.0f + __expf(-x)));
}
__device__ __forceinline__ float fsigm(float x) {
    return 1.0f / (1.0f + __expf(-x));
}
__device__ __forceinline__ void atomAddF(float* p, float v) {
    unsafeAtomicAdd(p, v);   // hardware global_atomic_add_f32
}

// ---------------------------------------------------------------------------
// Kernel A: weight transpose (fp32 [K][128] -> bf16 [128][K]) + dst histogram
// ---------------------------------------------------------------------------
struct PrepArgs { const float* src[10]; };

__global__ __launch_bounds__(256) void prep_hist_kernel(PrepArgs pa, short* __restrict__ wsb,
                                                        const int* __restrict__ lld,
                                                        const int* __restrict__ kld,
                                                        int* __restrict__ hist) {
    int idx = blockIdx.x * 256 + threadIdx.x;
    if (idx < 245760) {
        int pair = idx / 49152;
        int rem  = idx - pair * 49152;
        int second = (rem >= 32768) ? 1 : 0;
        int mi = pair * 2 + second;
        int within = second ? (rem - 32768) : rem;
        int n, k, K;
        if (second) { K = 128; n = within >> 7; k = within & 127; }
        else        { K = 256; n = within >> 8; k = within & 255; }
        int dstoff = pair * 49152 + second * 32768;
        wsb[dstoff + n * K + k] = (short)f2bf(pa.src[mi][k * 128 + n]);
        return;
    }
    idx -= 245760;
    if (idx < 320000) { atomicAdd(&hist[lld[idx]], 1); return; }
    idx -= 320000;
    if (idx < 160000) atomicAdd(&hist[10000 + kld[idx]], 1);
}

// ---------------------------------------------------------------------------
// Kernel B: exclusive scan of 10000 bins per edge type (LDS-staged, coalesced)
// ---------------------------------------------------------------------------
__global__ __launch_bounds__(256) void scan_kernel(const int* __restrict__ hist,
                                                   int* __restrict__ cursor) {
    __shared__ int bins[10000];
    __shared__ int ps[256];
    const int b = blockIdx.x, t = threadIdx.x;
    const int* h = hist + b * 10000;
    int* cur = cursor + b * 10000;
    for (int i = t; i < 10000; i += 256) bins[i] = h[i];
    __syncthreads();
    const int base = t * 40;
    int s = 0;
#pragma unroll 8
    for (int i = 0; i < 40; i++) { int ii = base + i; if (ii < 10000) s += bins[ii]; }
    ps[t] = s;
    __syncthreads();
    for (int off = 1; off < 256; off <<= 1) {
        int v = (t >= off) ? ps[t - off] : 0;
        __syncthreads();
        ps[t] += v;
        __syncthreads();
    }
    int run = ps[t] - s;   // exclusive prefix of this chunk
    for (int i = 0; i < 40; i++) {
        int ii = base + i;
        if (ii < 10000) { int c = bins[ii]; bins[ii] = run; run += c; }
    }
    __syncthreads();
    for (int i = t; i < 10000; i += 256) cur[i] = bins[i];
}

// ---------------------------------------------------------------------------
// Kernel C: fused scatter (blocks 0..1874) + projection GEMMs (blocks 1875..)
// proj: P = A @ W1part (+bias for dst tables), bf16 out [rows][256]
// ---------------------------------------------------------------------------
struct ProjDesc { const float* A; const short* Bt; short* out; const float* bias;
                  int rows; int ktb; int co; int hasb; };
struct CArgs {
    const int *lls, *lld, *kls, *kld;
    int* cursor;
    int *ll_ssrc, *ll_sdst, *kl_ssrc, *kl_sdst;
    ProjDesc d[8];
};

__global__ __launch_bounds__(256) void scatter_proj_kernel(CArgs ca) {
    __shared__ __align__(16) short a_lds[64 * MSTR];
    const int t = threadIdx.x;
    if (blockIdx.x < 1875) {
        int i = blockIdx.x * 256 + t;
        if (i < 320000) {
            int d = ca.lld[i];
            int p = atomicAdd(&ca.cursor[d], 1);
            ca.ll_ssrc[p] = ca.lls[i]; ca.ll_sdst[p] = d;
        } else if (i < 480000) {
            int j = i - 320000;
            int d = ca.kld[j];
            int p = atomicAdd(&ca.cursor[10000 + d], 1);
            ca.kl_ssrc[p] = ca.kls[j]; ca.kl_sdst[p] = d;
        }
        return;
    }
    const int pb = blockIdx.x - 1875;
    const int di = pb / 157, tile = pb - di * 157;
    const ProjDesc pd = ca.d[di];
    if (tile * 64 >= pd.rows) return;
    {
        const int r = t >> 2, q = t & 3;
        const int node = tile * 64 + r;
        short* arow = a_lds + r * MSTR + q * 32;
        if (node < pd.rows) {
            const float* ap = pd.A + (size_t)node * 128 + q * 32;
#pragma unroll
            for (int i = 0; i < 4; i++) {
                float4 v0 = *(const float4*)(ap + i * 8);
                float4 v1 = *(const float4*)(ap + i * 8 + 4);
                short8 o;
                o[0] = (short)f2bf(v0.x); o[1] = (short)f2bf(v0.y);
                o[2] = (short)f2bf(v0.z); o[3] = (short)f2bf(v0.w);
                o[4] = (short)f2bf(v1.x); o[5] = (short)f2bf(v1.y);
                o[6] = (short)f2bf(v1.z); o[7] = (short)f2bf(v1.w);
                *(short8*)(arow + i * 8) = o;
            }
        } else {
            short8 z = {0, 0, 0, 0, 0, 0, 0, 0};
#pragma unroll
            for (int i = 0; i < 4; i++) *(short8*)(arow + i * 8) = z;
        }
    }
    __syncthreads();

    const int ln = t & 63, wv = t >> 6;
    const int lrow = ln & 15, quad = ln >> 4;
    const int c0 = wv * 32 + lrow, c1 = c0 + 16;

    short8 bf0[4], bf1[4];
#pragma unroll
    for (int kt = 0; kt < 4; kt++) {
        bf0[kt] = *(const short8*)(pd.Bt + c0 * 256 + (pd.ktb + kt) * 32 + quad * 8);
        bf1[kt] = *(const short8*)(pd.Bt + c1 * 256 + (pd.ktb + kt) * 32 + quad * 8);
    }
    const float bb0 = pd.hasb ? pd.bias[c0] : 0.0f;
    const float bb1 = pd.hasb ? pd.bias[c1] : 0.0f;
#pragma unroll
    for (int mt = 0; mt < 4; mt++) {
        short8 af[4];
#pragma unroll
        for (int kt = 0; kt < 4; kt++)
            af[kt] = *(const short8*)(&a_lds[(mt * 16 + lrow) * MSTR + kt * 32 + quad * 8]);
        f32x4 a0 = {0.f, 0.f, 0.f, 0.f}, a1 = {0.f, 0.f, 0.f, 0.f};
#pragma unroll
        for (int kt = 0; kt < 4; kt++) {
            a0 = __builtin_amdgcn_mfma_f32_16x16x32_bf16(af[kt], bf0[kt], a0, 0, 0, 0);
            a1 = __builtin_amdgcn_mfma_f32_16x16x32_bf16(af[kt], bf1[kt], a1, 0, 0, 0);
        }
#pragma unroll
        for (int r = 0; r < 4; r++) {
            const int node = tile * 64 + mt * 16 + quad * 4 + r;
            if (node < pd.rows) {
                pd.out[(size_t)node * 256 + pd.co + c0] = (short)f2bf(a0[r] + bb0);
                pd.out[(size_t)node * 256 + pd.co + c1] = (short)f2bf(a1[r] + bb1);
            }
        }
    }
}

// ---------------------------------------------------------------------------
// Edge kernel: EPB=32, 256 threads (4 waves), wave w owns cols [32w,32w+32).
// LDS ~18.3 KB -> 8 blocks/CU. Gate folded into segmented scan.
// ---------------------------------------------------------------------------
struct EdgeSet {
    const short *Ps, *Pd;        // [nodes][256] bf16: 0..127 e-proj, 128..255 c-proj (b1 in Pd)
    const float *xs, *xd;
    const int *esrc, *edst;      // dst-sorted
    const float *w256e, *w256c;  // dij coefficient rows (fp32)
    const short *W2t, *cW2t;     // [128][128] bf16
    const float *b2e, *b2c;
    const float *aW, *ab, *cW3;
};
struct EdgePair { EdgeSet s[2]; int split; };

__global__ __launch_bounds__(256, 8) void edge_kernel(EdgePair ep,
                                                      float* __restrict__ hne,
                                                      float* __restrict__ xne)
{
    __shared__ __align__(16) char mbuf[EPB * MSTR * 4];  // 17408: mh|mc bf16, overlay msg f32 (16896)
    __shared__ float sv_l[EPB];
    __shared__ float gate_l[EPB];
    __shared__ float xdf[3][EPB];
    __shared__ int   dstl[EPB];
    __shared__ float gp[4][EPB];

    short* mh = (short*)mbuf;
    short* mc = (short*)(mbuf + EPB * MSTR * 2);
    float* msg = (float*)mbuf;          // stride 132 floats, overlays mh+mc after GEMMs

    const int isKL = (blockIdx.x >= ep.split) ? 1 : 0;
    const EdgeSet P = ep.s[isKL];
    const int eb = (blockIdx.x - (isKL ? ep.split : 0)) * EPB;
    const int t = threadIdx.x;

    // ---- phase 0: gather projections, fuse add+dij*w+silu, pack bf16 ----
    {
        const int e = t >> 3, q = t & 7;     // 8 threads/edge, 16 cols each
        const int eid = eb + e;
        const int s = P.esrc[eid], d = P.edst[eid];
        float dx = P.xs[s * 3 + 0] - P.xd[d * 3 + 0];
        float dy = P.xs[s * 3 + 1] - P.xd[d * 3 + 1];
        float dz = P.xs[s * 3 + 2] - P.xd[d * 3 + 2];
        float dd = sqrtf(dx * dx + dy * dy + dz * dz);
        if (q == 0) {
            dstl[e] = d;
            float inv = 1.0f / (dd + 1.0f);
            xdf[0][e] = dx * inv; xdf[1][e] = dy * inv; xdf[2][e] = dz * inv;
        }
        const short* psrow = P.Ps + (size_t)s * 256 + q * 16;
        const short* pdrow = P.Pd + (size_t)d * 256 + q * 16;
#pragma unroll
        for (int path = 0; path < 2; path++) {
            const short* ps = psrow + path * 128;
            const short* pq = pdrow + path * 128;
            const float* wq = (path ? P.w256c : P.w256e) + q * 16;
            short* mrow = (path ? mc : mh) + e * MSTR + q * 16;
#pragma unroll
            for (int i = 0; i < 2; i++) {
                short8 a = *(const short8*)(ps + i * 8);
                short8 b = *(const short8*)(pq + i * 8);
                float4 wA = *(const float4*)(wq + i * 8);
                float4 wB = *(const float4*)(wq + i * 8 + 4);
                short8 o;
                o[0] = (short)f2bf(fsilu(bf2f(a[0]) + bf2f(b[0]) + dd * wA.x));
                o[1] = (short)f2bf(fsilu(bf2f(a[1]) + bf2f(b[1]) + dd * wA.y));
                o[2] = (short)f2bf(fsilu(bf2f(a[2]) + bf2f(b[2]) + dd * wA.z));
                o[3] = (short)f2bf(fsilu(bf2f(a[3]) + bf2f(b[3]) + dd * wA.w));
                o[4] = (short)f2bf(fsilu(bf2f(a[4]) + bf2f(b[4]) + dd * wB.x));
                o[5] = (short)f2bf(fsilu(bf2f(a[5]) + bf2f(b[5]) + dd * wB.y));
                o[6] = (short)f2bf(fsilu(bf2f(a[6]) + bf2f(b[6]) + dd * wB.z));
                o[7] = (short)f2bf(fsilu(bf2f(a[7]) + bf2f(b[7]) + dd * wB.w));
                *(short8*)(mrow + i * 8) = o;
            }
        }
    }
    __syncthreads();   // B1

    const int ln = t & 63, wv = t >> 6;
    const int lrow = ln & 15, quad = ln >> 4;
    const int c0 = wv * 32 + lrow, c1 = c0 + 16;

    // ---- GEMM2c: c2 = silu(m_c @ cW2 + cb2); sv partials via butterfly ----
    {
        short8 bf0[4], bf1[4];
#pragma unroll
        for (int kt = 0; kt < 4; kt++) {
            bf0[kt] = *(const short8*)(P.cW2t + c0 * 128 + kt * 32 + quad * 8);
            bf1[kt] = *(const short8*)(P.cW2t + c1 * 128 + kt * 32 + quad * 8);
        }
        const float cw0 = P.cW3[c0], cw1 = P.cW3[c1];
        const float bb0 = P.b2c[c0], bb1 = P.b2c[c1];
#pragma unroll
        for (int mt = 0; mt < 2; mt++) {
            short8 af[4];
#pragma unroll
            for (int kt = 0; kt < 4; kt++)
                af[kt] = *(const short8*)(&mc[(mt * 16 + lrow) * MSTR + kt * 32 + quad * 8]);
            f32x4 a0 = {0.f, 0.f, 0.f, 0.f}, a1 = {0.f, 0.f, 0.f, 0.f};
#pragma unroll
            for (int kt = 0; kt < 4; kt++) {
                a0 = __builtin_amdgcn_mfma_f32_16x16x32_bf16(af[kt], bf0[kt], a0, 0, 0, 0);
                a1 = __builtin_amdgcn_mfma_f32_16x16x32_bf16(af[kt], bf1[kt], a1, 0, 0, 0);
            }
#pragma unroll
            for (int r = 0; r < 4; r++) {
                float v0 = fsilu(a0[r] + bb0);
                float v1 = fsilu(a1[r] + bb1);
                float g = v0 * cw0 + v1 * cw1;
                g += __shfl_xor(g, 1, 64);
                g += __shfl_xor(g, 2, 64);
                g += __shfl_xor(g, 4, 64);
                g += __shfl_xor(g, 8, 64);
                if (lrow == 0) gp[wv][mt * 16 + quad * 4 + r] = g;
            }
        }
    }
    __syncthreads();   // B2
    if (t < EPB) sv_l[t] = gp[0][t] + gp[1][t] + gp[2][t] + gp[3][t];
    __syncthreads();   // B3 (gp reused below)

    // ---- GEMM2e: m2 = silu(m_h @ eW2 + b2); gate partials; m2 kept in regs ----
    float m2s[2][8];
    {
        short8 bf0[4], bf1[4];
#pragma unroll
        for (int kt = 0; kt < 4; kt++) {
            bf0[kt] = *(const short8*)(P.W2t + c0 * 128 + kt * 32 + quad * 8);
            bf1[kt] = *(const short8*)(P.W2t + c1 * 128 + kt * 32 + quad * 8);
        }
        const float aw0 = P.aW[c0], aw1 = P.aW[c1];
        const float bb0 = P.b2e[c0], bb1 = P.b2e[c1];
#pragma unroll
        for (int mt = 0; mt < 2; mt++) {
            short8 af[4];
#pragma unroll
            for (int kt = 0; kt < 4; kt++)
                af[kt] = *(const short8*)(&mh[(mt * 16 + lrow) * MSTR + kt * 32 + quad * 8]);
            f32x4 a0 = {0.f, 0.f, 0.f, 0.f}, a1 = {0.f, 0.f, 0.f, 0.f};
#pragma unroll
            for (int kt = 0; kt < 4; kt++) {
                a0 = __builtin_amdgcn_mfma_f32_16x16x32_bf16(af[kt], bf0[kt], a0, 0, 0, 0);
                a1 = __builtin_amdgcn_mfma_f32_16x16x32_bf16(af[kt], bf1[kt], a1, 0, 0, 0);
            }
#pragma unroll
            for (int r = 0; r < 4; r++) {
                float v0 = fsilu(a0[r] + bb0);
                float v1 = fsilu(a1[r] + bb1);
                m2s[mt][r] = v0; m2s[mt][4 + r] = v1;
                float g = v0 * aw0 + v1 * aw1;
                g += __shfl_xor(g, 1, 64);
                g += __shfl_xor(g, 2, 64);
                g += __shfl_xor(g, 4, 64);
                g += __shfl_xor(g, 8, 64);
                if (lrow == 0) gp[wv][mt * 16 + quad * 4 + r] = g;
            }
        }
    }
    __syncthreads();   // B4 (all mh/mc reads done, gp complete -> overlay ok)
    if (t < EPB) gate_l[t] = fsigm(gp[0][t] + gp[1][t] + gp[2][t] + gp[3][t] + P.ab[0]);
#pragma unroll
    for (int mt = 0; mt < 2; mt++)
#pragma unroll
        for (int r = 0; r < 4; r++) {
            const int erow = mt * 16 + quad * 4 + r;
            msg[erow * 132 + c0] = m2s[mt][r];
            msg[erow * 132 + c1] = m2s[mt][4 + r];
        }
    __syncthreads();   // B5

    // ---- segmented reductions (dst-sorted); gate folded into h-scan ----
    if (t < 128) {
        const int col = t;
        float acc = 0.0f;
        int cur = dstl[0];
#pragma unroll 4
        for (int e = 0; e < EPB; e++) {
            const int d = dstl[e];
            if (d != cur) {
                atomAddF(&hne[(size_t)cur * 128 + col], acc);
                acc = 0.0f; cur = d;
            }
            acc += msg[e * 132 + col] * gate_l[e];
        }
        atomAddF(&hne[(size_t)cur * 128 + col], acc);
    } else if (t < 131) {
        const int ax = t - 128;
        float acc = 0.0f;
        int cur = dstl[0];
        for (int e = 0; e < EPB; e++) {
            const int d = dstl[e];
            if (d != cur) {
                atomAddF(&xne[cur * 3 + ax], acc);
                acc = 0.0f; cur = d;
            }
            acc += sv_l[e] * xdf[ax][e];
        }
        atomAddF(&xne[cur * 3 + ax], acc);
    }
}

// ---------------------------------------------------------------------------
// Node kernel (unchanged from R3)
// ---------------------------------------------------------------------------
__global__ __launch_bounds__(256) void node_kernel(
    const float* __restrict__ h_lig, const float* __restrict__ zlig,
    const short* __restrict__ W1t, const float* __restrict__ b1v,
    const short* __restrict__ W2t, const float* __restrict__ b2v,
    const float* __restrict__ x_lig,
    float* __restrict__ acc_h, float* __restrict__ acc_x)
{
    __shared__ __align__(16) short f_lds[64 * FSTR];
    __shared__ __align__(16) short m_lds[64 * MSTR];
    const int t = threadIdx.x;
    const int nb = blockIdx.x * 64;

    {
        const int e = t >> 2, q = t & 3;
        const int node = nb + e;
        short* frow = &f_lds[e * FSTR + q * 32];
        if (node < 10000) {
            const float zi = 1.0f / zlig[node];
            const float4* hp = (const float4*)(h_lig + (size_t)node * 128 + q * 32);
            const float4* np = (const float4*)(acc_h + (size_t)node * 128 + q * 32);
#pragma unroll
            for (int i = 0; i < 8; i++) {
                float4 v = hp[i];
                *(ushort4*)(frow + i * 4) =
                    make_ushort4(f2bf(v.x), f2bf(v.y), f2bf(v.z), f2bf(v.w));
            }
#pragma unroll
            for (int i = 0; i < 8; i++) {
                float4 v = np[i];
                *(ushort4*)(frow + 128 + i * 4) =
                    make_ushort4(f2bf(v.x * zi), f2bf(v.y * zi), f2bf(v.z * zi), f2bf(v.w * zi));
            }
        } else {
            const ushort4 zz = make_ushort4(0, 0, 0, 0);
#pragma unroll
            for (int i = 0; i < 8; i++) {
                *(ushort4*)(frow + i * 4) = zz;
                *(ushort4*)(frow + 128 + i * 4) = zz;
            }
        }
    }
    __syncthreads();

    const int ln = t & 63, wv = t >> 6;
    const int lrow = ln & 15, quad = ln >> 4;
    const int c0 = wv * 32 + lrow, c1 = c0 + 16;

    {
        short8 bf0[8], bf1[8];
#pragma unroll
        for (int kt = 0; kt < 8; kt++) {
            bf0[kt] = *(const short8*)(W1t + c0 * 256 + kt * 32 + quad * 8);
            bf1[kt] = *(const short8*)(W1t + c1 * 256 + kt * 32 + quad * 8);
        }
        const float bb0 = b1v[c0], bb1 = b1v[c1];
#pragma unroll
        for (int mt = 0; mt < 4; mt++) {
            short8 af[8];
#pragma unroll
            for (int kt = 0; kt < 8; kt++)
                af[kt] = *(const short8*)(&f_lds[(mt * 16 + lrow) * FSTR + kt * 32 + quad * 8]);
            f32x4 a0 = {0.f, 0.f, 0.f, 0.f}, a1 = {0.f, 0.f, 0.f, 0.f};
#pragma unroll
            for (int kt = 0; kt < 8; kt++) {
                a0 = __builtin_amdgcn_mfma_f32_16x16x32_bf16(af[kt], bf0[kt], a0, 0, 0, 0);
                a1 = __builtin_amdgcn_mfma_f32_16x16x32_bf16(af[kt], bf1[kt], a1, 0, 0, 0);
            }
#pragma unroll
            for (int r = 0; r < 4; r++) {
                const int erow = mt * 16 + quad * 4 + r;
                m_lds[erow * MSTR + c0] = (short)f2bf(fsilu(a0[r] + bb0));
                m_lds[erow * MSTR + c1] = (short)f2bf(fsilu(a1[r] + bb1));
            }
        }
    }
    __syncthreads();

    {
        short8 bf0[4], bf1[4];
#pragma unroll
        for (int kt = 0; kt < 4; kt++) {
            bf0[kt] = *(const short8*)(W2t + c0 * 128 + kt * 32 + quad * 8);
            bf1[kt] = *(const short8*)(W2t + c1 * 128 + kt * 32 + quad * 8);
        }
        const float bb0 = b2v[c0], bb1 = b2v[c1];
#pragma unroll
        for (int mt = 0; mt < 4; mt++) {
            short8 af[4];
#pragma unroll
            for (int kt = 0; kt < 4; kt++)
                af[kt] = *(const short8*)(&m_lds[(mt * 16 + lrow) * MSTR + kt * 32 + quad * 8]);
            f32x4 a0 = {0.f, 0.f, 0.f, 0.f}, a1 = {0.f, 0.f, 0.f, 0.f};
#pragma unroll
            for (int kt = 0; kt < 4; kt++) {
                a0 = __builtin_amdgcn_mfma_f32_16x16x32_bf16(af[kt], bf0[kt], a0, 0, 0, 0);
                a1 = __builtin_amdgcn_mfma_f32_16x16x32_bf16(af[kt], bf1[kt], a1, 0, 0, 0);
            }
#pragma unroll
            for (int r = 0; r < 4; r++) {
                const int node = nb + mt * 16 + quad * 4 + r;
                if (node < 10000) {
                    acc_h[(size_t)node * 128 + c0] = a0[r] + bb0 + h_lig[(size_t)node * 128 + c0];
                    acc_h[(size_t)node * 128 + c1] = a1[r] + bb1 + h_lig[(size_t)node * 128 + c1];
                }
            }
        }
    }
    if (t < 64) {
        const int node = nb + t;
        if (node < 10000) {
            const float zi = 1.0f / zlig[node];
#pragma unroll
            for (int i = 0; i < 3; i++)
                acc_x[node * 3 + i] = x_lig[node * 3 + i] + acc_x[node * 3 + i] * zi;
        }
    }
}

extern "C" void kernel_launch(void* const* d_in, const int* in_sizes, int n_in,
                              void* d_out, int out_size, void* d_ws, size_t ws_size,
                              hipStream_t stream)
{
    (void)in_sizes; (void)n_in; (void)ws_size;
    const float* h_lig  = (const float*)d_in[0];
    const float* h_kp   = (const float*)d_in[1];
    const float* x_lig  = (const float*)d_in[2];
    const float* x_kp   = (const float*)d_in[3];
    const float* z_lig  = (const float*)d_in[4];
    const float* ll_eW1 = (const float*)d_in[5];
    const float* ll_eb1 = (const float*)d_in[6];
    const float* ll_eW2 = (const float*)d_in[7];
    const float* ll_eb2 = (const float*)d_in[8];
    const float* ll_aW  = (const float*)d_in[9];
    const float* ll_ab  = (const float*)d_in[10];
    const float* ll_cW1 = (const float*)d_in[11];
    const float* ll_cb1 = (const float*)d_in[12];
    const float* ll_cW2 = (const float*)d_in[13];
    const float* ll_cb2 = (const float*)d_in[14];
    const float* ll_cW3 = (const float*)d_in[15];
    const float* kl_eW1 = (const float*)d_in[16];
    const float* kl_eb1 = (const float*)d_in[17];
    const float* kl_eW2 = (const float*)d_in[18];
    const float* kl_eb2 = (const float*)d_in[19];
    const float* kl_aW  = (const float*)d_in[20];
    const float* kl_ab  = (const float*)d_in[21];
    const float* kl_cW1 = (const float*)d_in[22];
    const float* kl_cb1 = (const float*)d_in[23];
    const float* kl_cW2 = (const float*)d_in[24];
    const float* kl_cb2 = (const float*)d_in[25];
    const float* kl_cW3 = (const float*)d_in[26];
    const float* n_W1   = (const float*)d_in[27];
    const float* n_b1   = (const float*)d_in[28];
    const float* n_W2   = (const float*)d_in[29];
    const float* n_b2   = (const float*)d_in[30];
    const int* ll_src = (const int*)d_in[31];
    const int* ll_dst = (const int*)d_in[32];
    const int* kl_src = (const int*)d_in[33];
    const int* kl_dst = (const int*)d_in[34];

    float* out = (float*)d_out;
    float* hne = out;                 // [10000,128]
    float* xne = out + 1280000;       // [10000,3]

    // ws layout (bytes) — ~20.9 MB total
    char* wsc = (char*)d_ws;
    short* wsb    = (short*)wsc;                 //       0: weights (491,520 B)
    short* P_ll_s = (short*)(wsc +   491520);    // 5,120,000 B  [10000][256]
    short* P_ll_d = (short*)(wsc +  5611520);    // 5,120,000 B
    short* P_kl_s = (short*)(wsc + 10731520);    // 1,024,000 B  [2000][256]
    short* P_kl_d = (short*)(wsc + 11755520);    // 5,120,000 B
    int* ll_ssrc  = (int*)(wsc + 16875520);      // 1,280,000 B
    int* ll_sdst  = (int*)(wsc + 18155520);      // 1,280,000 B
    int* kl_ssrc  = (int*)(wsc + 19435520);      //   640,000 B
    int* kl_sdst  = (int*)(wsc + 20075520);      //   640,000 B
    int* hist     = (int*)(wsc + 20715520);      //    80,000 B (20000 ints)
    int* cursor   = (int*)(wsc + 20795520);      //    80,000 B -> end 20,875,520

    hipMemsetAsync(d_out, 0, (size_t)out_size * sizeof(float), stream);
    hipMemsetAsync(hist, 0, 80000, stream);

    // A. weight transpose + histogram
    {
        PrepArgs pa;
        pa.src[0] = ll_eW1; pa.src[1] = ll_eW2; pa.src[2] = ll_cW1; pa.src[3] = ll_cW2;
        pa.src[4] = kl_eW1; pa.src[5] = kl_eW2; pa.src[6] = kl_cW1; pa.src[7] = kl_cW2;
        pa.src[8] = n_W1;   pa.src[9] = n_W2;
        prep_hist_kernel<<<2835, 256, 0, stream>>>(pa, wsb, ll_dst, kl_dst, hist);
    }
    // B. scan
    scan_kernel<<<2, 256, 0, stream>>>(hist, cursor);
    // C. scatter + projections fused
    {
        CArgs ca;
        ca.lls = ll_src; ca.lld = ll_dst; ca.kls = kl_src; ca.kld = kl_dst;
        ca.cursor = cursor;
        ca.ll_ssrc = ll_ssrc; ca.ll_sdst = ll_sdst;
        ca.kl_ssrc = kl_ssrc; ca.kl_sdst = kl_sdst;
        ca.d[0] = { h_lig, wsb + 0,      P_ll_s, ll_eb1, 10000, 0, 0,   0 };
        ca.d[1] = { h_lig, wsb + 49152,  P_ll_s, ll_cb1, 10000, 0, 128, 0 };
        ca.d[2] = { h_lig, wsb + 0,      P_ll_d, ll_eb1, 10000, 4, 0,   1 };
        ca.d[3] = { h_lig, wsb + 49152,  P_ll_d, ll_cb1, 10000, 4, 128, 1 };
        ca.d[4] = { h_kp,  wsb + 98304,  P_kl_s, kl_eb1,  2000, 0, 0,   0 };
        ca.d[5] = { h_kp,  wsb + 147456, P_kl_s, kl_cb1,  2000, 0, 128, 0 };
        ca.d[6] = { h_lig, wsb + 98304,  P_kl_d, kl_eb1, 10000, 4, 0,   1 };
        ca.d[7] = { h_lig, wsb + 147456, P_kl_d, kl_cb1, 10000, 4, 128, 1 };
        scatter_proj_kernel<<<1875 + 8 * 157, 256, 0, stream>>>(ca);
    }
    // D. edges (ll + kl in one launch), EPB=32
    {
        EdgePair ep;
        ep.split = 10000;
        ep.s[0] = { P_ll_s, P_ll_d, x_lig, x_lig, ll_ssrc, ll_sdst,
                    ll_eW1 + 256 * 128, ll_cW1 + 256 * 128,
                    wsb + 32768, wsb + 81920, ll_eb2, ll_cb2,
                    ll_aW, ll_ab, ll_cW3 };
        ep.s[1] = { P_kl_s, P_kl_d, x_kp, x_lig, kl_ssrc, kl_sdst,
                    kl_eW1 + 256 * 128, kl_cW1 + 256 * 128,
                    wsb + 131072, wsb + 180224, kl_eb2, kl_cb2,
                    kl_aW, kl_ab, kl_cW3 };
        edge_kernel<<<15000, 256, 0, stream>>>(ep, hne, xne);
    }
    // E. node MLP + final outputs
    node_kernel<<<157, 256, 0, stream>>>(
        h_lig, z_lig, wsb + 196608, n_b1, wsb + 229376, n_b2,
        x_lig, hne, xne);
}